// Round 12
// baseline (2792.666 us; speedup 1.0000x reference)
//
#include <hip/hip_runtime.h>

typedef _Float16 f16;
typedef _Float16 f16x2 __attribute__((ext_vector_type(2)));
typedef _Float16 f16x8 __attribute__((ext_vector_type(8)));
typedef float f32x4 __attribute__((ext_vector_type(4)));

#define B_ 64
#define S_ 1024
#define I_ 64
#define H_ 256
#define G_ 1024      // 4*H
#define M_ 65536     // B*S

// ======================= Threefry-2x32-20 (JAX) =======================
__device__ __forceinline__ unsigned rotl32(unsigned x, int r){ return (x<<r)|(x>>(32-r)); }

__device__ __forceinline__ void threefry(unsigned k0, unsigned k1, unsigned& x0, unsigned& x1){
  unsigned k2 = k0 ^ k1 ^ 0x1BD11BDAu;
  x0 += k0; x1 += k1;
  x0 += x1; x1 = rotl32(x1,13); x1 ^= x0;
  x0 += x1; x1 = rotl32(x1,15); x1 ^= x0;
  x0 += x1; x1 = rotl32(x1,26); x1 ^= x0;
  x0 += x1; x1 = rotl32(x1, 6); x1 ^= x0;
  x0 += k1; x1 += k2 + 1u;
  x0 += x1; x1 = rotl32(x1,17); x1 ^= x0;
  x0 += x1; x1 = rotl32(x1,29); x1 ^= x0;
  x0 += x1; x1 = rotl32(x1,16); x1 ^= x0;
  x0 += x1; x1 = rotl32(x1,24); x1 ^= x0;
  x0 += k2; x1 += k0 + 2u;
  x0 += x1; x1 = rotl32(x1,13); x1 ^= x0;
  x0 += x1; x1 = rotl32(x1,15); x1 ^= x0;
  x0 += x1; x1 = rotl32(x1,26); x1 ^= x0;
  x0 += x1; x1 = rotl32(x1, 6); x1 ^= x0;
  x0 += k0; x1 += k1 + 3u;
  x0 += x1; x1 = rotl32(x1,17); x1 ^= x0;
  x0 += x1; x1 = rotl32(x1,29); x1 ^= x0;
  x0 += x1; x1 = rotl32(x1,16); x1 ^= x0;
  x0 += x1; x1 = rotl32(x1,24); x1 ^= x0;
  x0 += k1; x1 += k2 + 4u;
  x0 += x1; x1 = rotl32(x1,13); x1 ^= x0;
  x0 += x1; x1 = rotl32(x1,15); x1 ^= x0;
  x0 += x1; x1 = rotl32(x1,26); x1 ^= x0;
  x0 += x1; x1 = rotl32(x1, 6); x1 ^= x0;
  x0 += k2; x1 += k0 + 5u;
}

// XLA ErfInv32 (Giles)
__device__ __forceinline__ float erfinv_f(float x){
  float w = -log1pf(-x*x);
  float p;
  if (w < 5.f){
    w -= 2.5f;
    p = 2.81022636e-08f;
    p = fmaf(p,w, 3.43273939e-07f);
    p = fmaf(p,w,-3.5233877e-06f);
    p = fmaf(p,w,-4.39150654e-06f);
    p = fmaf(p,w, 0.00021858087f);
    p = fmaf(p,w,-0.00125372503f);
    p = fmaf(p,w,-0.00417768164f);
    p = fmaf(p,w, 0.246640727f);
    p = fmaf(p,w, 1.50140941f);
  } else {
    w = sqrtf(w) - 3.f;
    p = -0.000200214257f;
    p = fmaf(p,w, 0.000100950558f);
    p = fmaf(p,w, 0.00134934322f);
    p = fmaf(p,w,-0.00367342844f);
    p = fmaf(p,w, 0.00573950773f);
    p = fmaf(p,w,-0.0076224613f);
    p = fmaf(p,w, 0.00943887047f);
    p = fmaf(p,w, 1.00167406f);
    p = fmaf(p,w, 2.83297682f);
  }
  return p*x;
}

__device__ __forceinline__ float jax_normal_from_bits(unsigned bits){
  unsigned fb = (bits >> 9) | 0x3f800000u;
  float f = __uint_as_float(fb) - 1.0f;                 // [0,1)
  const float lo = -0.9999999403953552f;                // nextafter(-1,0)
  float u = fmaf(f, 2.0f, lo);
  u = fmaxf(lo, u);
  return 1.4142135623730951f * erfinv_f(u);
}

// psiP[j] = pack(half(cos(theta+tn)), half(sin(phi+pn))), j = k*256+n
__global__ __launch_bounds__(256) void prep_psi(const float* __restrict__ theta,
                                                const float* __restrict__ phi,
                                                unsigned* __restrict__ psiP){
  int j = blockIdx.x*256 + threadIdx.x;  // 0..16383
  unsigned a0=0u, a1=0u; threefry(0u,42u,a0,a1);   // k1 (theta noise)
  unsigned b0=0u, b1=1u; threefry(0u,42u,b0,b1);   // k2 (phi noise)
  unsigned t0=0u, t1=(unsigned)j; threefry(a0,a1,t0,t1);
  unsigned p0=0u, p1=(unsigned)j; threefry(b0,b1,p0,p1);
  float tn = 0.01f * jax_normal_from_bits(t0^t1);
  float pn = 0.01f * jax_normal_from_bits(p0^p1);
  float cr = cosf(theta[j] + tn);
  float ci = sinf(phi[j]   + pn);
  f16x2 pk; pk.x = (f16)cr; pk.y = (f16)ci;
  psiP[j] = __builtin_bit_cast(unsigned, pk);
}

// ======================= weight packing =======================
// ROUND-12: remap baked into the pack. Slot s holds gate row
// rmap(s) = (s&3)*256 + (s>>2), so lstm_core indexes all W by plain tid
// (fully coalesced — r11 scattered these loads via rmp and regressed).
// WhT4[l][kk][slot] = 8 f16 of W_hh[l][rmap(slot)][8kk..8kk+7]
__global__ __launch_bounds__(256) void pack_wh(const float* __restrict__ Whh,
                                               uint4* __restrict__ WhT4){
  int idx = blockIdx.x*256 + threadIdx.x;     // 0..65535
  int l   = idx >> 15;
  int slot= (idx >> 5) & 1023;
  int kk  = idx & 31;
  int row = (slot & 3)*256 + (slot >> 2);
  const float* src = Whh + ((size_t)(l*1024 + row))*256 + kk*8;
  f16x8 tmp;
  #pragma unroll
  for (int j=0;j<8;j++) tmp[j] = (f16)src[j];
  WhT4[l*32768 + kk*1024 + slot] = __builtin_bit_cast(uint4, tmp);
}

__global__ __launch_bounds__(256) void pack_wi_bias(const float* __restrict__ Wih,
                                                    const float* __restrict__ bih,
                                                    const float* __restrict__ bhh,
                                                    f16* __restrict__ WiH,
                                                    float* __restrict__ biasS){
  int idx = blockIdx.x*256 + threadIdx.x;     // 0..524287
  WiH[idx] = (f16)Wih[idx];
  if (idx < 2048) biasS[idx] = bih[idx] + bhh[idx];
}

__global__ __launch_bounds__(128) void zero_prog(int* __restrict__ p){
  p[threadIdx.x] = 0;    // prog1[0..63] ++ prog2[0..63] (contiguous, 256B-aligned each)
}

// ======================= quantum phase =======================
__global__ __launch_bounds__(256) void quantum_k(const float* __restrict__ x,
                                                 const unsigned* __restrict__ psiP,
                                                 f16* __restrict__ yq){
  __shared__ float xs[64];
  int m = blockIdx.x;
  int n = threadIdx.x;
  if (n < 64) xs[n] = x[(size_t)m*64 + n];
  __syncthreads();
  float ar=0.f, ai=0.f;
  #pragma unroll 8
  for (int k=0;k<64;k++){
    unsigned p = psiP[k*256 + n];
    f16x2 pk = __builtin_bit_cast(f16x2, p);
    float xv = xs[k];
    ar = fmaf(xv, (float)pk.x, ar);
    ai = fmaf(xv, (float)pk.y, ai);
  }
  yq[(size_t)m*256 + n] = (f16)sqrtf(ar*ar + ai*ai);
}

// ======================= pre-activation GEMM (MFMA f16, layer 1 only) =======================
__global__ __launch_bounds__(256,2) void pre_gemm(const f16* __restrict__ A,
                                                  const f16* __restrict__ W,
                                                  const float* __restrict__ bias,
                                                  f16* __restrict__ out){
  const int m0 = blockIdx.x*64;
  const int n0 = blockIdx.y*512;
  __shared__ f16 As[64*264];
  const int tid = threadIdx.x;
  #pragma unroll
  for (int it=0; it<8; ++it){
    int u = tid + it*256;
    int row = u >> 5, ko = u & 31;
    f16x8 v = *(const f16x8*)(A + (size_t)(m0+row)*256 + ko*8);
    *(f16x8*)(&As[row*264 + ko*8]) = v;
  }
  __syncthreads();
  const int wave = tid >> 6, lane = tid & 63;
  const int n_w = n0 + wave*128;
  const int lr = lane & 15, lk = (lane>>4)*8;
  f32x4 acc[4][8] = {};
  for (int ks=0; ks<8; ++ks){
    f16x8 a[4];
    #pragma unroll
    for (int mt=0; mt<4; ++mt)
      a[mt] = *(const f16x8*)(&As[(mt*16+lr)*264 + ks*32 + lk]);
    #pragma unroll
    for (int nt=0; nt<8; ++nt){
      f16x8 b = *(const f16x8*)(W + (size_t)(n_w + nt*16 + lr)*256 + ks*32 + lk);
      #pragma unroll
      for (int mt=0; mt<4; ++mt)
        acc[mt][nt] = __builtin_amdgcn_mfma_f32_16x16x32_f16(a[mt], b, acc[mt][nt], 0,0,0);
    }
  }
  const int col = lr, rbase = (lane>>4)*4;
  #pragma unroll
  for (int nt=0; nt<8; ++nt){
    float bv = bias[n_w + nt*16 + col];
    #pragma unroll
    for (int mt=0; mt<4; ++mt){
      #pragma unroll
      for (int j=0; j<4; ++j){
        int m = m0 + mt*16 + rbase + j;
        out[(size_t)m*1024 + n_w + nt*16 + col] = (f16)(acc[mt][nt][j] + bv);
      }
    }
  }
}

// ======================= LSTM recurrence =======================
__device__ __forceinline__ float sigm_f(float x){
  x = fminf(fmaxf(x,-30.f),30.f);
  return 1.f/(1.f + __expf(-x));
}
__device__ __forceinline__ float tanh_f(float x){
  x = fminf(fmaxf(x,-15.f),15.f);
  float e = __expf(-2.f*x);
  return (1.f-e)/(1.f+e);
}
__device__ __forceinline__ float dot2f(unsigned w, unsigned h, float acc){
#if __has_builtin(__builtin_amdgcn_fdot2)
  return __builtin_amdgcn_fdot2(__builtin_bit_cast(f16x2,w), __builtin_bit_cast(f16x2,h), acc, false);
#else
  float d;
  asm("v_dot2_f32_f16 %0, %1, %2, %3" : "=v"(d) : "v"(w), "v"(h), "v"(acc));
  return d;
#endif
}

__device__ __forceinline__ f32x4 mfma16(uint4 a, uint4 b, f32x4 c){
  return __builtin_amdgcn_mfma_f32_16x16x32_f16(
      __builtin_bit_cast(f16x8, a), __builtin_bit_cast(f16x8, b), c, 0, 0, 0);
}

// One LSTM layer for one batch on one CU (16 waves).
// ROUND-12 = r11's one-barrier quad-remap structure, UN-CONFOUNDED:
// the remap is baked into pack_wh, so every W access (w[23] init, wlds
// staging, 4 streamed quads/step) indexes by plain tid — coalescing
// byte-identical to r8. Only the 2B/lane pre load uses rmp (4x32B
// segments/wave, prefetched a full step ahead). Thread tid owns gate row
// rmap(tid)=(tid&3)*256+(tid>>2): the 4 gates {i,f,g,o} of element e=tid>>2
// sit in adjacent lanes of one quad -> gate gather = 4 intra-wave shuffles,
// c/h update in lane tid&3==0, ONE __syncthreads per step. No gbuf, no
// idle-wave phase. Per-value arithmetic identical to r8 (same kk order).
template<int WRITE_ALL, int CONSUME>
__device__ __forceinline__
void lstm_core(const f16* __restrict__ preB,    // [1024][1024] f16 (this batch)
               const uint4* __restrict__ Wh,    // [32][1024] uint4 (this layer, remapped)
               f16* __restrict__ outh,          // [1024][256] (this batch) if WRITE_ALL
               f16* __restrict__ hfin_p,        // [256] if !WRITE_ALL
               int* __restrict__ prog_rel,
               int* __restrict__ prog_acq,
               uint4* wlds, uint4* h4)          // h4: [2][32] double buffer
{
  const int tid  = threadIdx.x;
  const int rmp  = (tid & 3)*256 + (tid >> 2);   // this thread's gate row (pre index)
  const int lane = tid & 63;
  const int qb   = lane & ~3;                    // quad base lane
  const int gt   = tid & 3;                      // 0:i 1:f 2:g 3:o
  const int e    = tid >> 2;                     // element 0..255

  uint4 w[23];
  #pragma unroll
  for (int j=0;j<23;++j) w[j] = Wh[j*1024 + tid];
  #pragma unroll
  for (int j=0;j<5;++j)  wlds[j*1024 + tid] = Wh[(23+j)*1024 + tid];
  if (tid < 64) h4[tid] = make_uint4(0u,0u,0u,0u);   // zero both h buffers
  float c = 0.f;

  if (CONSUME){
    if (tid==0){
      while (__hip_atomic_load(prog_acq, __ATOMIC_ACQUIRE, __HIP_MEMORY_SCOPE_AGENT) < 1)
        __builtin_amdgcn_s_sleep(8);
    }
  }
  __syncthreads();

  float pv = (float)preB[rmp];
  const uint4* wstr = Wh + 28*1024 + tid;        // streamed quads 28..31 (coalesced)

  for (int t=0; t<1024; ++t){
    if (CONSUME){
      if ((t&15)==15 && t<1023){                 // about to prefetch into next chunk
        if (tid==0){
          const int need = ((t+1)>>4) + 1;
          while (__hip_atomic_load(prog_acq, __ATOMIC_ACQUIRE, __HIP_MEMORY_SCOPE_AGENT) < need)
            __builtin_amdgcn_s_sleep(8);
        }
        __syncthreads();
      }
    }
    float pn = (t < 1023) ? (float)preB[(size_t)(t+1)*1024 + rmp] : 0.f;
    // issue the 4 streamed W quads early; consumed at the end of the dot chain
    uint4 s0 = wstr[0];
    uint4 s1 = wstr[1024];
    uint4 s2 = wstr[2048];
    uint4 s3 = wstr[3072];
    float a0 = pv, a1 = 0.f;

    const uint4* hr = h4 + (t&1)*32;             // h(t-1)
    // distance-2 rotating prefetch of the h broadcast + the 5 LDS weight quads
    uint4 hb0 = hr[0], hb1 = hr[1];
    uint4 ub0 = wlds[tid], ub1 = wlds[1024 + tid];

    #pragma unroll
    for (int kk=0; kk<23; ++kk){
      uint4 hp = (kk & 1) ? hb1 : hb0;
      if (kk & 1) hb1 = hr[kk+2]; else hb0 = hr[kk+2];   // kk+2 <= 24 < 32
      a0 = dot2f(w[kk].x, hp.x, a0); a1 = dot2f(w[kk].y, hp.y, a1);
      a0 = dot2f(w[kk].z, hp.z, a0); a1 = dot2f(w[kk].w, hp.w, a1);
    }
    #pragma unroll
    for (int j=0; j<5; ++j){
      const int kk = 23 + j;                             // 23..27
      uint4 hp = (kk & 1) ? hb1 : hb0;
      if (kk & 1) hb1 = hr[kk+2]; else hb0 = hr[kk+2];   // kk+2 <= 29 < 32
      uint4 u = (j & 1) ? ub1 : ub0;
      if (j + 2 < 5){ if (j & 1) ub1 = wlds[(j+2)*1024 + tid]; else ub0 = wlds[(j+2)*1024 + tid]; }
      a0 = dot2f(u.x, hp.x, a0); a1 = dot2f(u.y, hp.y, a1);
      a0 = dot2f(u.z, hp.z, a0); a1 = dot2f(u.w, hp.w, a1);
    }
    #pragma unroll
    for (int j=0; j<4; ++j){
      const int kk = 28 + j;                             // 28..31
      uint4 hp = (kk & 1) ? hb1 : hb0;
      if (kk + 2 < 32){ if (kk & 1) hb1 = hr[kk+2]; else hb0 = hr[kk+2]; }
      const uint4 u = (j==0) ? s0 : (j==1) ? s1 : (j==2) ? s2 : s3;
      a0 = dot2f(u.x, hp.x, a0); a1 = dot2f(u.y, hp.y, a1);
      a0 = dot2f(u.z, hp.z, a0); a1 = dot2f(u.w, hp.w, a1);
    }

    // activation (per-lane; divergent but value-exact — same math as before)
    const float raw = a0 + a1;
    const float act = (gt == 2) ? tanh_f(raw) : sigm_f(raw);

    // quad gather: lanes qb..qb+3 hold i,f,g,o of element e
    const float iv = __shfl(act, qb + 0, 64);
    const float fv = __shfl(act, qb + 1, 64);
    const float gv = __shfl(act, qb + 2, 64);
    const float ov = __shfl(act, qb + 3, 64);

    if (gt == 0){
      c = fmaf(fv, c, iv*gv);
      const float h = ov * tanh_f(c);
      const f16 hf = (f16)h;
      ((f16*)(h4 + ((t+1)&1)*32))[e] = hf;
      if (WRITE_ALL) outh[(size_t)t*256 + e] = hf;
      else if (t == 1023) hfin_p[e] = hf;
    }
    __syncthreads();   // single barrier: h(t) visible + all stores drained
    if (WRITE_ALL){
      if ((t&15)==15 && tid==0){
        __threadfence();                         // make h chunk agent-visible
        __hip_atomic_store(prog_rel, t+1, __ATOMIC_RELEASE, __HIP_MEMORY_SCOPE_AGENT);
      }
    }
    pv = pn;
  }
}

// Layer-2 input GEMM role: per 16-step chunk, pre2[t][gate] = h1[t] @ W_ih2^T + bias2.
// pre2b ALIASES pre1: chunk c (rows 16c..16c+15) is written only after
// prog1 >= 16(c+1) -> WAR-safe (see round-4 notes).
__device__ __forceinline__
void gemm_role(const f16* __restrict__ h1b,     // [1024][256] this batch
               const f16* __restrict__ W2,      // [1024][256] f16 (layer-2 W_ih)
               const float* __restrict__ bias2, // [1024]
               f16* __restrict__ pre2b,         // [1024][1024] this batch (aliases pre1)
               int* __restrict__ prog1b,
               int* __restrict__ prog2b)
{
  const int tid  = threadIdx.x;
  const int w    = tid >> 6, lane = tid & 63;
  const int lr   = lane & 15, lq = lane >> 4;
  for (int cidx=0; cidx<64; ++cidx){
    if (tid==0){
      while (__hip_atomic_load(prog1b, __ATOMIC_ACQUIRE, __HIP_MEMORY_SCOPE_AGENT) < 16*(cidx+1))
        __builtin_amdgcn_s_sleep(8);
    }
    __syncthreads();
    const int t0 = cidx*16;
    const f16* Ab = h1b + ((size_t)(t0 + lr))*256 + lq*8;
    uint4 af[8];
    #pragma unroll
    for (int ks=0; ks<8; ++ks) af[ks] = *(const uint4*)(Ab + ks*32);
    #pragma unroll
    for (int nt=0; nt<4; ++nt){
      f32x4 acc = {0.f,0.f,0.f,0.f};
      const int gate = w*64 + nt*16 + lr;
      const f16* Bb = W2 + (size_t)gate*256 + lq*8;
      #pragma unroll
      for (int ks=0; ks<8; ++ks){
        const uint4 bf = *(const uint4*)(Bb + ks*32);
        acc = mfma16(af[ks], bf, acc);
      }
      const float bv = bias2[gate];
      #pragma unroll
      for (int j=0; j<4; ++j){
        const int t = t0 + lq*4 + j;
        pre2b[(size_t)t*1024 + gate] = (f16)(acc[j] + bv);
      }
    }
    asm volatile("s_waitcnt vmcnt(0)" ::: "memory");
    __syncthreads();
    if (tid==0){
      __threadfence();
      __hip_atomic_store(prog2b, cidx+1, __ATOMIC_RELEASE, __HIP_MEMORY_SCOPE_AGENT);
    }
  }
}

// ======================= fused two-layer pipeline =======================
// 192 blocks (~81 KB LDS, 1024 thr -> 1 block/CU; 192 <= 256 so all co-resident):
//   blocks   0..63  : layer-1 LSTM (producer of h1)
//   blocks  64..127 : layer-2 input GEMM (h1 -> pre2), 16-step chunks
//   blocks 128..191 : layer-2 LSTM (consumer of pre2)
// One-directional dataflow, monotone progress counters -> deadlock-free.
__global__ __launch_bounds__(1024, 4)
void pipeline_k(const f16* __restrict__ pre1,
                const uint4* __restrict__ WhT4,
                const f16* __restrict__ W2,      // WiH + 262144
                const float* __restrict__ biasS,
                f16* __restrict__ h1,
                f16* __restrict__ pre2,          // == pre1 (alias)
                f16* __restrict__ hfin,
                int* __restrict__ prog1,
                int* __restrict__ prog2)
{
  __shared__ __align__(16) uint4 wlds[5*1024];   // 80 KB
  __shared__ __align__(16) uint4 h4[64];         // 1 KB: h double buffer [2][32]
  const int bid = blockIdx.x;
  if (bid < 64){
    const int b = bid;
    lstm_core<1,0>(pre1 + (size_t)b*1024*1024, WhT4,
                   h1 + (size_t)b*1024*256, nullptr,
                   prog1 + b, nullptr, wlds, h4);
  } else if (bid < 128){
    const int b = bid - 64;
    gemm_role(h1 + (size_t)b*1024*256, W2, biasS + 1024,
              pre2 + (size_t)b*1024*1024, prog1 + b, prog2 + b);
  } else {
    const int b = bid - 128;
    lstm_core<0,1>(pre2 + (size_t)b*1024*1024, WhT4 + 32768,
                   nullptr, hfin + b*256,
                   nullptr, prog2 + b, wlds, h4);
  }
}

// ======================= final FC =======================
__global__ __launch_bounds__(64) void fc_k(const f16* __restrict__ hfin,
                                           const float* __restrict__ Wfc,
                                           const float* __restrict__ bfc,
                                           float* __restrict__ out){
  int b = blockIdx.x, k = threadIdx.x;
  float a = 0.f;
  #pragma unroll
  for (int j=0;j<4;j++){
    int idx = k + 64*j;
    a += (float)hfin[b*256 + idx] * Wfc[idx];
  }
  #pragma unroll
  for (int off=32; off; off>>=1) a += __shfl_down(a, off);
  if (k==0) out[b] = a + bfc[0];
}

// ======================= launch =======================
extern "C" void kernel_launch(void* const* d_in, const int* in_sizes, int n_in,
                              void* d_out, int out_size, void* d_ws, size_t ws_size,
                              hipStream_t stream) {
  const float* x     = (const float*)d_in[0];
  const float* theta = (const float*)d_in[1];
  const float* phi   = (const float*)d_in[2];
  const float* Wih   = (const float*)d_in[3];
  const float* Whh   = (const float*)d_in[4];
  const float* bih   = (const float*)d_in[5];
  const float* bhh   = (const float*)d_in[6];
  const float* Wfc   = (const float*)d_in[7];
  const float* bfc   = (const float*)d_in[8];
  float* out = (float*)d_out;

  char* ws = (char*)d_ws;
  size_t off = 0;
  auto take = [&](size_t bytes){ size_t r = off; off += (bytes + 255) & ~(size_t)255; return r; };
  // Total ~203.6 MB (round-0's proven 203.5 MB + 512 B of progress counters).
  f16*      pre1  = (f16*)     (ws + take((size_t)M_*1024*2));   // 134 MB
  f16*      pre2  = pre1;                                        // ALIAS (WAR-safe, see gemm_role)
  f16*      yq    = (f16*)     (ws + take((size_t)M_*256*2));    // 33.5 MB
  f16*      h1    = (f16*)     (ws + take((size_t)M_*256*2));    // 33.5 MB
  unsigned* psiP  = (unsigned*)(ws + take((size_t)16384*4));
  uint4*    WhT4  = (uint4*)   (ws + take((size_t)2*32768*16));  // 1 MB
  f16*      WiH   = (f16*)     (ws + take((size_t)2*262144*2));  // 1 MB
  float*    biasS = (float*)   (ws + take((size_t)2048*4));
  f16*      hfin  = (f16*)     (ws + take((size_t)64*256*2));
  int*      prog1 = (int*)     (ws + take((size_t)64*4));
  int*      prog2 = (int*)     (ws + take((size_t)64*4));        // contiguous after prog1

  zero_prog   <<<1,    128, 0, stream>>>(prog1);
  prep_psi    <<<64,   256, 0, stream>>>(theta, phi, psiP);
  pack_wh     <<<256,  256, 0, stream>>>(Whh, WhT4);
  pack_wi_bias<<<2048, 256, 0, stream>>>(Wih, bih, bhh, WiH, biasS);
  quantum_k   <<<65536,256, 0, stream>>>(x, psiP, yq);

  dim3 gg(1024, 2);
  pre_gemm <<<gg, 256, 0, stream>>>(yq, WiH, biasS, pre1);   // layer-1 input GEMM

  pipeline_k <<<192, 1024, 0, stream>>>(pre1, WhT4, WiH + 262144, biasS,
                                        h1, pre2, hfin, prog1, prog2);

  fc_k <<<64, 64, 0, stream>>>(hfin, Wfc, bfc, out);
}

// Round 13
// 2610.481 us; speedup vs baseline: 1.0698x; 1.0698x over previous
//
#include <hip/hip_runtime.h>

typedef _Float16 f16;
typedef _Float16 f16x2 __attribute__((ext_vector_type(2)));
typedef _Float16 f16x8 __attribute__((ext_vector_type(8)));
typedef float f32x4 __attribute__((ext_vector_type(4)));

#define B_ 64
#define S_ 1024
#define I_ 64
#define H_ 256
#define G_ 1024      // 4*H
#define M_ 65536     // B*S

// ======================= Threefry-2x32-20 (JAX) =======================
__device__ __forceinline__ unsigned rotl32(unsigned x, int r){ return (x<<r)|(x>>(32-r)); }

__device__ __forceinline__ void threefry(unsigned k0, unsigned k1, unsigned& x0, unsigned& x1){
  unsigned k2 = k0 ^ k1 ^ 0x1BD11BDAu;
  x0 += k0; x1 += k1;
  x0 += x1; x1 = rotl32(x1,13); x1 ^= x0;
  x0 += x1; x1 = rotl32(x1,15); x1 ^= x0;
  x0 += x1; x1 = rotl32(x1,26); x1 ^= x0;
  x0 += x1; x1 = rotl32(x1, 6); x1 ^= x0;
  x0 += k1; x1 += k2 + 1u;
  x0 += x1; x1 = rotl32(x1,17); x1 ^= x0;
  x0 += x1; x1 = rotl32(x1,29); x1 ^= x0;
  x0 += x1; x1 = rotl32(x1,16); x1 ^= x0;
  x0 += x1; x1 = rotl32(x1,24); x1 ^= x0;
  x0 += k2; x1 += k0 + 2u;
  x0 += x1; x1 = rotl32(x1,13); x1 ^= x0;
  x0 += x1; x1 = rotl32(x1,15); x1 ^= x0;
  x0 += x1; x1 = rotl32(x1,26); x1 ^= x0;
  x0 += x1; x1 = rotl32(x1, 6); x1 ^= x0;
  x0 += k0; x1 += k1 + 3u;
  x0 += x1; x1 = rotl32(x1,17); x1 ^= x0;
  x0 += x1; x1 = rotl32(x1,29); x1 ^= x0;
  x0 += x1; x1 = rotl32(x1,16); x1 ^= x0;
  x0 += x1; x1 = rotl32(x1,24); x1 ^= x0;
  x0 += k1; x1 += k2 + 4u;
  x0 += x1; x1 = rotl32(x1,13); x1 ^= x0;
  x0 += x1; x1 = rotl32(x1,15); x1 ^= x0;
  x0 += x1; x1 = rotl32(x1,26); x1 ^= x0;
  x0 += x1; x1 = rotl32(x1, 6); x1 ^= x0;
  x0 += k2; x1 += k0 + 5u;
}

// XLA ErfInv32 (Giles)
__device__ __forceinline__ float erfinv_f(float x){
  float w = -log1pf(-x*x);
  float p;
  if (w < 5.f){
    w -= 2.5f;
    p = 2.81022636e-08f;
    p = fmaf(p,w, 3.43273939e-07f);
    p = fmaf(p,w,-3.5233877e-06f);
    p = fmaf(p,w,-4.39150654e-06f);
    p = fmaf(p,w, 0.00021858087f);
    p = fmaf(p,w,-0.00125372503f);
    p = fmaf(p,w,-0.00417768164f);
    p = fmaf(p,w, 0.246640727f);
    p = fmaf(p,w, 1.50140941f);
  } else {
    w = sqrtf(w) - 3.f;
    p = -0.000200214257f;
    p = fmaf(p,w, 0.000100950558f);
    p = fmaf(p,w, 0.00134934322f);
    p = fmaf(p,w,-0.00367342844f);
    p = fmaf(p,w, 0.00573950773f);
    p = fmaf(p,w,-0.0076224613f);
    p = fmaf(p,w, 0.00943887047f);
    p = fmaf(p,w, 1.00167406f);
    p = fmaf(p,w, 2.83297682f);
  }
  return p*x;
}

__device__ __forceinline__ float jax_normal_from_bits(unsigned bits){
  unsigned fb = (bits >> 9) | 0x3f800000u;
  float f = __uint_as_float(fb) - 1.0f;                 // [0,1)
  const float lo = -0.9999999403953552f;                // nextafter(-1,0)
  float u = fmaf(f, 2.0f, lo);
  u = fmaxf(lo, u);
  return 1.4142135623730951f * erfinv_f(u);
}

// psiP[j] = pack(half(cos(theta+tn)), half(sin(phi+pn))), j = k*256+n
__global__ __launch_bounds__(256) void prep_psi(const float* __restrict__ theta,
                                                const float* __restrict__ phi,
                                                unsigned* __restrict__ psiP){
  int j = blockIdx.x*256 + threadIdx.x;  // 0..16383
  unsigned a0=0u, a1=0u; threefry(0u,42u,a0,a1);   // k1 (theta noise)
  unsigned b0=0u, b1=1u; threefry(0u,42u,b0,b1);   // k2 (phi noise)
  unsigned t0=0u, t1=(unsigned)j; threefry(a0,a1,t0,t1);
  unsigned p0=0u, p1=(unsigned)j; threefry(b0,b1,p0,p1);
  float tn = 0.01f * jax_normal_from_bits(t0^t1);
  float pn = 0.01f * jax_normal_from_bits(p0^p1);
  float cr = cosf(theta[j] + tn);
  float ci = sinf(phi[j]   + pn);
  f16x2 pk; pk.x = (f16)cr; pk.y = (f16)ci;
  psiP[j] = __builtin_bit_cast(unsigned, pk);
}

// ======================= weight packing =======================
// WhT4[l][kk][row] = 8 f16 of W_hh[l][row][8kk..8kk+7]  (coalesced per-kk loads)
__global__ __launch_bounds__(256) void pack_wh(const float* __restrict__ Whh,
                                               uint4* __restrict__ WhT4){
  int idx = blockIdx.x*256 + threadIdx.x;     // 0..65535
  int l   = idx >> 15;
  int row = (idx >> 5) & 1023;
  int kk  = idx & 31;
  const float* src = Whh + ((size_t)(l*1024 + row))*256 + kk*8;
  f16x8 tmp;
  #pragma unroll
  for (int j=0;j<8;j++) tmp[j] = (f16)src[j];
  WhT4[l*32768 + kk*1024 + row] = __builtin_bit_cast(uint4, tmp);
}

__global__ __launch_bounds__(256) void pack_wi_bias(const float* __restrict__ Wih,
                                                    const float* __restrict__ bih,
                                                    const float* __restrict__ bhh,
                                                    f16* __restrict__ WiH,
                                                    float* __restrict__ biasS){
  int idx = blockIdx.x*256 + threadIdx.x;     // 0..524287
  WiH[idx] = (f16)Wih[idx];
  if (idx < 2048) biasS[idx] = bih[idx] + bhh[idx];
}

__global__ __launch_bounds__(128) void zero_prog(int* __restrict__ p){
  p[threadIdx.x] = 0;    // prog1[0..63] ++ prog2[0..63] (contiguous, 256B-aligned each)
}

// ======================= quantum phase =======================
__global__ __launch_bounds__(256) void quantum_k(const float* __restrict__ x,
                                                 const unsigned* __restrict__ psiP,
                                                 f16* __restrict__ yq){
  __shared__ float xs[64];
  int m = blockIdx.x;
  int n = threadIdx.x;
  if (n < 64) xs[n] = x[(size_t)m*64 + n];
  __syncthreads();
  float ar=0.f, ai=0.f;
  #pragma unroll 8
  for (int k=0;k<64;k++){
    unsigned p = psiP[k*256 + n];
    f16x2 pk = __builtin_bit_cast(f16x2, p);
    float xv = xs[k];
    ar = fmaf(xv, (float)pk.x, ar);
    ai = fmaf(xv, (float)pk.y, ai);
  }
  yq[(size_t)m*256 + n] = (f16)sqrtf(ar*ar + ai*ai);
}

// ======================= pre-activation GEMM (MFMA f16, layer 1 only) =======================
__global__ __launch_bounds__(256,2) void pre_gemm(const f16* __restrict__ A,
                                                  const f16* __restrict__ W,
                                                  const float* __restrict__ bias,
                                                  f16* __restrict__ out){
  const int m0 = blockIdx.x*64;
  const int n0 = blockIdx.y*512;
  __shared__ f16 As[64*264];
  const int tid = threadIdx.x;
  #pragma unroll
  for (int it=0; it<8; ++it){
    int u = tid + it*256;
    int row = u >> 5, ko = u & 31;
    f16x8 v = *(const f16x8*)(A + (size_t)(m0+row)*256 + ko*8);
    *(f16x8*)(&As[row*264 + ko*8]) = v;
  }
  __syncthreads();
  const int wave = tid >> 6, lane = tid & 63;
  const int n_w = n0 + wave*128;
  const int lr = lane & 15, lk = (lane>>4)*8;
  f32x4 acc[4][8] = {};
  for (int ks=0; ks<8; ++ks){
    f16x8 a[4];
    #pragma unroll
    for (int mt=0; mt<4; ++mt)
      a[mt] = *(const f16x8*)(&As[(mt*16+lr)*264 + ks*32 + lk]);
    #pragma unroll
    for (int nt=0; nt<8; ++nt){
      f16x8 b = *(const f16x8*)(W + (size_t)(n_w + nt*16 + lr)*256 + ks*32 + lk);
      #pragma unroll
      for (int mt=0; mt<4; ++mt)
        acc[mt][nt] = __builtin_amdgcn_mfma_f32_16x16x32_f16(a[mt], b, acc[mt][nt], 0,0,0);
    }
  }
  const int col = lr, rbase = (lane>>4)*4;
  #pragma unroll
  for (int nt=0; nt<8; ++nt){
    float bv = bias[n_w + nt*16 + col];
    #pragma unroll
    for (int mt=0; mt<4; ++mt){
      #pragma unroll
      for (int j=0; j<4; ++j){
        int m = m0 + mt*16 + rbase + j;
        out[(size_t)m*1024 + n_w + nt*16 + col] = (f16)(acc[mt][nt][j] + bv);
      }
    }
  }
}

// ======================= LSTM recurrence =======================
__device__ __forceinline__ float sigm_f(float x){
  x = fminf(fmaxf(x,-30.f),30.f);
  return 1.f/(1.f + __expf(-x));
}
__device__ __forceinline__ float tanh_f(float x){
  x = fminf(fmaxf(x,-15.f),15.f);
  float e = __expf(-2.f*x);
  return (1.f-e)/(1.f+e);
}
__device__ __forceinline__ float dot2f(unsigned w, unsigned h, float acc){
#if __has_builtin(__builtin_amdgcn_fdot2)
  return __builtin_amdgcn_fdot2(__builtin_bit_cast(f16x2,w), __builtin_bit_cast(f16x2,h), acc, false);
#else
  // guarantee the HW dot2 (the cvt+fma fallback is 3x the VALU issue)
  float d;
  asm("v_dot2_f32_f16 %0, %1, %2, %3" : "=v"(d) : "v"(w), "v"(h), "v"(acc));
  return d;
#endif
}

__device__ __forceinline__ f32x4 mfma16(uint4 a, uint4 b, f32x4 c){
  return __builtin_amdgcn_mfma_f32_16x16x32_f16(
      __builtin_bit_cast(f16x8, a), __builtin_bit_cast(f16x8, b), c, 0, 0, 0);
}

// One LSTM layer for one batch on one CU (16 waves, 1 gate row per thread).
// W row split: 23 uint4 in VGPRs/AGPRs + 5 uint4 in LDS (80 KB) + 4 uint4
// streamed per-step from WhT4 (L2-resident). Two barriers/step, wave-uniform
// activation branch (tid>>8), gbuf gate exchange. This is the measured best
// (r8, 2597us); rounds 9-12 falsified: remat-pin (null), 4 acc chains (null),
// quad-remap one-barrier (regressed: intra-quad divergent activation +
// shuffles cost more than the saved barrier).
// WRITE_ALL=1: producer role — writes h to outh, releases prog_rel every 16 steps.
// CONSUME=1:  consumer role — polls prog_acq before touching each 16-step chunk.
template<int WRITE_ALL, int CONSUME>
__device__ __forceinline__
void lstm_core(const f16* __restrict__ preB,    // [1024][1024] f16 (this batch)
               const uint4* __restrict__ Wh,    // [32][1024] uint4 (this layer)
               f16* __restrict__ outh,          // [1024][256] (this batch) if WRITE_ALL
               f16* __restrict__ hfin_p,        // [256] if !WRITE_ALL
               int* __restrict__ prog_rel,
               int* __restrict__ prog_acq,
               uint4* wlds, uint4* h4, float* gbuf)
{
  const int tid = threadIdx.x;                   // gate row
  uint4 w[23];
  #pragma unroll
  for (int j=0;j<23;++j) w[j] = Wh[j*1024 + tid];
  #pragma unroll
  for (int j=0;j<5;++j)  wlds[j*1024 + tid] = Wh[(23+j)*1024 + tid];
  if (tid < 32) h4[tid] = make_uint4(0u,0u,0u,0u);
  float c = 0.f;

  if (CONSUME){
    if (tid==0){
      while (__hip_atomic_load(prog_acq, __ATOMIC_ACQUIRE, __HIP_MEMORY_SCOPE_AGENT) < 1)
        __builtin_amdgcn_s_sleep(8);
    }
  }
  __syncthreads();

  float pv = (float)preB[tid];
  const int gtype = tid >> 8;                    // 0:i 1:f 2:g 3:o (wave-uniform)
  const uint4* wstr = Wh + 28*1024 + tid;        // streamed quads 28..31

  for (int t=0; t<1024; ++t){
    if (CONSUME){
      if ((t&15)==15 && t<1023){                 // about to prefetch into next chunk
        if (tid==0){
          const int need = ((t+1)>>4) + 1;
          while (__hip_atomic_load(prog_acq, __ATOMIC_ACQUIRE, __HIP_MEMORY_SCOPE_AGENT) < need)
            __builtin_amdgcn_s_sleep(8);
        }
        __syncthreads();
      }
    }
    float pn = (t < 1023) ? (float)preB[(size_t)(t+1)*1024 + tid] : 0.f;
    // issue the 4 streamed W quads early; consumed at the end of the dot chain
    uint4 s0 = wstr[0];
    uint4 s1 = wstr[1024];
    uint4 s2 = wstr[2048];
    uint4 s3 = wstr[3072];
    float a0 = pv, a1 = 0.f;

    // distance-2 rotating prefetch of the h broadcast + the 5 LDS weight quads
    uint4 hb0 = h4[0], hb1 = h4[1];
    uint4 ub0 = wlds[tid], ub1 = wlds[1024 + tid];

    #pragma unroll
    for (int kk=0; kk<23; ++kk){
      uint4 hp = (kk & 1) ? hb1 : hb0;
      if (kk & 1) hb1 = h4[kk+2]; else hb0 = h4[kk+2];   // kk+2 <= 24 < 32
      a0 = dot2f(w[kk].x, hp.x, a0); a1 = dot2f(w[kk].y, hp.y, a1);
      a0 = dot2f(w[kk].z, hp.z, a0); a1 = dot2f(w[kk].w, hp.w, a1);
    }
    #pragma unroll
    for (int j=0; j<5; ++j){
      const int kk = 23 + j;                             // 23..27
      uint4 hp = (kk & 1) ? hb1 : hb0;
      if (kk & 1) hb1 = h4[kk+2]; else hb0 = h4[kk+2];   // kk+2 <= 29 < 32
      uint4 u = (j & 1) ? ub1 : ub0;
      if (j + 2 < 5){ if (j & 1) ub1 = wlds[(j+2)*1024 + tid]; else ub0 = wlds[(j+2)*1024 + tid]; }
      a0 = dot2f(u.x, hp.x, a0); a1 = dot2f(u.y, hp.y, a1);
      a0 = dot2f(u.z, hp.z, a0); a1 = dot2f(u.w, hp.w, a1);
    }
    #pragma unroll
    for (int j=0; j<4; ++j){
      const int kk = 28 + j;                             // 28..31
      uint4 hp = (kk & 1) ? hb1 : hb0;
      if (kk + 2 < 32){ if (kk & 1) hb1 = h4[kk+2]; else hb0 = h4[kk+2]; }
      const uint4 u = (j==0) ? s0 : (j==1) ? s1 : (j==2) ? s2 : s3;
      a0 = dot2f(u.x, hp.x, a0); a1 = dot2f(u.y, hp.y, a1);
      a0 = dot2f(u.z, hp.z, a0); a1 = dot2f(u.w, hp.w, a1);
    }

    {
      const float raw = a0 + a1;
      gbuf[tid] = (gtype == 2) ? tanh_f(raw) : sigm_f(raw);
    }
    __syncthreads();
    if (tid < 256){
      float i_ = gbuf[tid];
      float f_ = gbuf[256+tid];
      float g_ = gbuf[512+tid];
      float o_ = gbuf[768+tid];
      c = fmaf(f_, c, i_*g_);
      float h = o_ * tanh_f(c);
      ((f16*)h4)[tid] = (f16)h;
      if (WRITE_ALL) outh[(size_t)t*256 + tid] = (f16)h;
      else if (t == 1023) hfin_p[tid] = (f16)h;
    }
    __syncthreads();   // drains all waves' loads AND stores (barrier implies full waitcnt)
    if (WRITE_ALL){
      if ((t&15)==15 && tid==0){
        __threadfence();                         // make h chunk agent-visible
        __hip_atomic_store(prog_rel, t+1, __ATOMIC_RELEASE, __HIP_MEMORY_SCOPE_AGENT);
      }
    }
    pv = pn;
  }
}

// Layer-2 input GEMM role: per 16-step chunk, pre2[t][gate] = h1[t] @ W_ih2^T + bias2.
// M=16 (timesteps), N=1024 (gates), K=256. Same MFMA shape, same K-accumulate order,
// same f16 rounding as pre_gemm -> bit-identical to the previous two-pass version.
// pre2b ALIASES pre1: chunk c (rows 16c..16c+15) is written only after
// prog1 >= 16(c+1), i.e. after the L1 LSTM has loaded rows <= 16c+16 (its
// loads drain at the end-of-step barrier BEFORE the release) and it never
// re-reads them -> WAR-safe.
__device__ __forceinline__
void gemm_role(const f16* __restrict__ h1b,     // [1024][256] this batch
               const f16* __restrict__ W2,      // [1024][256] f16 (layer-2 W_ih)
               const float* __restrict__ bias2, // [1024]
               f16* __restrict__ pre2b,         // [1024][1024] this batch (aliases pre1)
               int* __restrict__ prog1b,
               int* __restrict__ prog2b)
{
  const int tid  = threadIdx.x;
  const int w    = tid >> 6, lane = tid & 63;
  const int lr   = lane & 15, lq = lane >> 4;
  for (int cidx=0; cidx<64; ++cidx){
    if (tid==0){
      while (__hip_atomic_load(prog1b, __ATOMIC_ACQUIRE, __HIP_MEMORY_SCOPE_AGENT) < 16*(cidx+1))
        __builtin_amdgcn_s_sleep(8);
    }
    __syncthreads();
    const int t0 = cidx*16;
    const f16* Ab = h1b + ((size_t)(t0 + lr))*256 + lq*8;
    uint4 af[8];
    #pragma unroll
    for (int ks=0; ks<8; ++ks) af[ks] = *(const uint4*)(Ab + ks*32);
    #pragma unroll
    for (int nt=0; nt<4; ++nt){
      f32x4 acc = {0.f,0.f,0.f,0.f};
      const int gate = w*64 + nt*16 + lr;
      const f16* Bb = W2 + (size_t)gate*256 + lq*8;
      #pragma unroll
      for (int ks=0; ks<8; ++ks){
        const uint4 bf = *(const uint4*)(Bb + ks*32);
        acc = mfma16(af[ks], bf, acc);
      }
      const float bv = bias2[gate];
      #pragma unroll
      for (int j=0; j<4; ++j){
        const int t = t0 + lq*4 + j;
        pre2b[(size_t)t*1024 + gate] = (f16)(acc[j] + bv);
      }
    }
    asm volatile("s_waitcnt vmcnt(0)" ::: "memory");
    __syncthreads();
    if (tid==0){
      __threadfence();
      __hip_atomic_store(prog2b, cidx+1, __ATOMIC_RELEASE, __HIP_MEMORY_SCOPE_AGENT);
    }
  }
}

// ======================= fused two-layer pipeline =======================
// 192 blocks (~86 KB LDS, 1024 thr -> 1 block/CU; 192 <= 256 so all co-resident):
//   blocks   0..63  : layer-1 LSTM (producer of h1)
//   blocks  64..127 : layer-2 input GEMM (h1 -> pre2), 16-step chunks
//   blocks 128..191 : layer-2 LSTM (consumer of pre2)
// Dataflow is strictly one-directional (producers never wait on consumers),
// progress counters are monotone (no slot reuse) -> deadlock/livelock-free
// even under arbitrary dispatch order. Blocks b, b+64, b+128 land on the same
// XCD (same index mod 8) so chunk handoffs stay in one L2.
// __launch_bounds__(1024, 4): 4 waves/EU min -> 128-reg/wave unified budget.
__global__ __launch_bounds__(1024, 4)
void pipeline_k(const f16* __restrict__ pre1,
                const uint4* __restrict__ WhT4,
                const f16* __restrict__ W2,      // WiH + 262144
                const float* __restrict__ biasS,
                f16* __restrict__ h1,
                f16* __restrict__ pre2,          // == pre1 (alias)
                f16* __restrict__ hfin,
                int* __restrict__ prog1,
                int* __restrict__ prog2)
{
  __shared__ __align__(16) uint4 wlds[5*1024];   // 80 KB
  __shared__ __align__(16) uint4 h4[32];
  __shared__ float gbuf[1024];
  const int bid = blockIdx.x;
  if (bid < 64){
    const int b = bid;
    lstm_core<1,0>(pre1 + (size_t)b*1024*1024, WhT4,
                   h1 + (size_t)b*1024*256, nullptr,
                   prog1 + b, nullptr, wlds, h4, gbuf);
  } else if (bid < 128){
    const int b = bid - 64;
    gemm_role(h1 + (size_t)b*1024*256, W2, biasS + 1024,
              pre2 + (size_t)b*1024*1024, prog1 + b, prog2 + b);
  } else {
    const int b = bid - 128;
    lstm_core<0,1>(pre2 + (size_t)b*1024*1024, WhT4 + 32768,
                   nullptr, hfin + b*256,
                   nullptr, prog2 + b, wlds, h4, gbuf);
  }
}

// ======================= final FC =======================
__global__ __launch_bounds__(64) void fc_k(const f16* __restrict__ hfin,
                                           const float* __restrict__ Wfc,
                                           const float* __restrict__ bfc,
                                           float* __restrict__ out){
  int b = blockIdx.x, k = threadIdx.x;
  float a = 0.f;
  #pragma unroll
  for (int j=0;j<4;j++){
    int idx = k + 64*j;
    a += (float)hfin[b*256 + idx] * Wfc[idx];
  }
  #pragma unroll
  for (int off=32; off; off>>=1) a += __shfl_down(a, off);
  if (k==0) out[b] = a + bfc[0];
}

// ======================= launch =======================
extern "C" void kernel_launch(void* const* d_in, const int* in_sizes, int n_in,
                              void* d_out, int out_size, void* d_ws, size_t ws_size,
                              hipStream_t stream) {
  const float* x     = (const float*)d_in[0];
  const float* theta = (const float*)d_in[1];
  const float* phi   = (const float*)d_in[2];
  const float* Wih   = (const float*)d_in[3];
  const float* Whh   = (const float*)d_in[4];
  const float* bih   = (const float*)d_in[5];
  const float* bhh   = (const float*)d_in[6];
  const float* Wfc   = (const float*)d_in[7];
  const float* bfc   = (const float*)d_in[8];
  float* out = (float*)d_out;

  char* ws = (char*)d_ws;
  size_t off = 0;
  auto take = [&](size_t bytes){ size_t r = off; off += (bytes + 255) & ~(size_t)255; return r; };
  // Total ~203.6 MB (round-0's proven 203.5 MB + 512 B of progress counters).
  f16*      pre1  = (f16*)     (ws + take((size_t)M_*1024*2));   // 134 MB
  f16*      pre2  = pre1;                                        // ALIAS (WAR-safe, see gemm_role)
  f16*      yq    = (f16*)     (ws + take((size_t)M_*256*2));    // 33.5 MB
  f16*      h1    = (f16*)     (ws + take((size_t)M_*256*2));    // 33.5 MB
  unsigned* psiP  = (unsigned*)(ws + take((size_t)16384*4));
  uint4*    WhT4  = (uint4*)   (ws + take((size_t)2*32768*16));  // 1 MB
  f16*      WiH   = (f16*)     (ws + take((size_t)2*262144*2));  // 1 MB
  float*    biasS = (float*)   (ws + take((size_t)2048*4));
  f16*      hfin  = (f16*)     (ws + take((size_t)64*256*2));
  int*      prog1 = (int*)     (ws + take((size_t)64*4));
  int*      prog2 = (int*)     (ws + take((size_t)64*4));        // contiguous after prog1

  zero_prog   <<<1,    128, 0, stream>>>(prog1);
  prep_psi    <<<64,   256, 0, stream>>>(theta, phi, psiP);
  pack_wh     <<<256,  256, 0, stream>>>(Whh, WhT4);
  pack_wi_bias<<<2048, 256, 0, stream>>>(Wih, bih, bhh, WiH, biasS);
  quantum_k   <<<65536,256, 0, stream>>>(x, psiP, yq);

  dim3 gg(1024, 2);
  pre_gemm <<<gg, 256, 0, stream>>>(yq, WiH, biasS, pre1);   // layer-1 input GEMM

  pipeline_k <<<192, 1024, 0, stream>>>(pre1, WhT4, WiH + 262144, biasS,
                                        h1, pre2, hfin, prog1, prog2);

  fc_k <<<64, 64, 0, stream>>>(hfin, Wfc, bfc, out);
}